// Round 4
// baseline (1280.863 us; speedup 1.0000x reference)
//
#include <hip/hip_runtime.h>
#include <cstdint>
#include <cstddef>

typedef __bf16 bf16_t;
typedef __bf16 bf16x8 __attribute__((ext_vector_type(8)));
typedef float floatx4 __attribute__((ext_vector_type(4)));

static constexpr int T_TOK = 4096;
static constexpr int HDIM  = 2048;
static constexpr int DDIM  = 1024;
static constexpr int ESH   = 2;
static constexpr int ERT   = 16;
static constexpr int NPAIR = 2 * T_TOK;         // 8192
static constexpr int NPAIR_PAD = NPAIR + 128;   // pad so tile over-reads stay in-bounds

__device__ __forceinline__ float gelu_f(float v) {
  return 0.5f * v * (1.0f + erff(v * 0.70710678118654752440f));
}

// ---------------- router: logits -> softmax -> top2, atomic counts ----------------
__global__ __launch_bounds__(256) void router_kernel(
    const float* __restrict__ x, const float* __restrict__ Wr,
    int* __restrict__ top_e, float* __restrict__ top_w, int* __restrict__ counts)
{
  const int t = blockIdx.x;
  const int tid = threadIdx.x;
  float acc[ERT];
#pragma unroll
  for (int e = 0; e < ERT; ++e) acc[e] = 0.f;
  const float* xr = x + (long)t * HDIM;
  for (int h = tid; h < HDIM; h += 256) {
    const float xv = xr[h];
    const float4* w4 = (const float4*)(Wr + h * ERT);
    const float4 w0 = w4[0], w1 = w4[1], w2 = w4[2], w3 = w4[3];
    acc[0]  += xv * w0.x; acc[1]  += xv * w0.y; acc[2]  += xv * w0.z; acc[3]  += xv * w0.w;
    acc[4]  += xv * w1.x; acc[5]  += xv * w1.y; acc[6]  += xv * w1.z; acc[7]  += xv * w1.w;
    acc[8]  += xv * w2.x; acc[9]  += xv * w2.y; acc[10] += xv * w2.z; acc[11] += xv * w2.w;
    acc[12] += xv * w3.x; acc[13] += xv * w3.y; acc[14] += xv * w3.z; acc[15] += xv * w3.w;
  }
  __shared__ float s[256][ERT + 1];
#pragma unroll
  for (int e = 0; e < ERT; ++e) s[tid][e] = acc[e];
  __syncthreads();
  for (int st = 128; st >= 1; st >>= 1) {
    if (tid < st) {
#pragma unroll
      for (int e = 0; e < ERT; ++e) s[tid][e] += s[tid + st][e];
    }
    __syncthreads();
  }
  if (tid == 0) {
    float l[ERT];
    float mx = -1e30f;
#pragma unroll
    for (int e = 0; e < ERT; ++e) { l[e] = s[0][e]; mx = fmaxf(mx, l[e]); }
    float sum = 0.f;
#pragma unroll
    for (int e = 0; e < ERT; ++e) { l[e] = expf(l[e] - mx); sum += l[e]; }
    const float inv = 1.f / sum;
    float v0 = -1.f, v1 = -1.f; int i0 = 0, i1 = 0;
#pragma unroll
    for (int e = 0; e < ERT; ++e) {
      const float p = l[e] * inv;
      if (p > v0) { v1 = v0; i1 = i0; v0 = p; i0 = e; }
      else if (p > v1) { v1 = p; i1 = e; }
    }
    top_e[2 * t] = i0; top_e[2 * t + 1] = i1;
    top_w[2 * t] = v0; top_w[2 * t + 1] = v1;
    atomicAdd(&counts[i0], 1); atomicAdd(&counts[i1], 1);
  }
}

// ---------------- tiny prefix sum over 16 experts ----------------
__global__ void prefix_kernel(const int* __restrict__ counts, int* __restrict__ offsets) {
  if (threadIdx.x == 0) {
    int s = 0;
    for (int e = 0; e < ERT; ++e) { offsets[e] = s; s += counts[e]; }
    offsets[ERT] = s;
  }
}

// ---------------- scatter tokens into per-expert contiguous slots ----------------
__global__ __launch_bounds__(256) void scatter_kernel(
    const int* __restrict__ top_e, const float* __restrict__ top_w,
    const int* __restrict__ offsets, int* __restrict__ cursor,
    int* __restrict__ pair_token, float* __restrict__ pair_w,
    int* __restrict__ inv_slot)
{
  const int t = blockIdx.x * 256 + threadIdx.x;
  if (t >= T_TOK) return;
#pragma unroll
  for (int k = 0; k < 2; ++k) {
    const int e = top_e[2 * t + k];
    const int pos = atomicAdd(&cursor[e], 1);
    const int slot = offsets[e] + pos;
    pair_token[slot] = t;
    pair_w[slot] = top_w[2 * t + k];
    inv_slot[2 * t + k] = slot;
  }
}

// ---------------- x fp32 -> bf16 ----------------
__global__ __launch_bounds__(256) void cast_x_kernel(const float* __restrict__ x, bf16_t* __restrict__ xb) {
  const long base = (long)blockIdx.x * HDIM + threadIdx.x * 8;
  const float4 a = *(const float4*)(x + base);
  const float4 b = *(const float4*)(x + base + 4);
  bf16x8 v;
  v[0] = (__bf16)a.x; v[1] = (__bf16)a.y; v[2] = (__bf16)a.z; v[3] = (__bf16)a.w;
  v[4] = (__bf16)b.x; v[5] = (__bf16)b.y; v[6] = (__bf16)b.z; v[7] = (__bf16)b.w;
  *(bf16x8*)(xb + base) = v;
}

// ---------------- gather routed rows (fp32 -> bf16) ----------------
__global__ __launch_bounds__(256) void gather_kernel(
    const float* __restrict__ x, const int* __restrict__ pair_token, bf16_t* __restrict__ xg)
{
  const int slot = blockIdx.x;
  const int tok = pair_token[slot];
  const float* src = x + (long)tok * HDIM;
  const int c = threadIdx.x * 8;
  const float4 a = *(const float4*)(src + c);
  const float4 b = *(const float4*)(src + c + 4);
  bf16x8 v;
  v[0] = (__bf16)a.x; v[1] = (__bf16)a.y; v[2] = (__bf16)a.z; v[3] = (__bf16)a.w;
  v[4] = (__bf16)b.x; v[5] = (__bf16)b.y; v[6] = (__bf16)b.z; v[7] = (__bf16)b.w;
  *(bf16x8*)(xg + (long)slot * HDIM + c) = v;
}

// ---------------- transpose + cast: in fp32 [R][C] -> out bf16 [C][R], per mat ----------------
__global__ __launch_bounds__(256) void transpose_cast_kernel(
    const float* __restrict__ in, bf16_t* __restrict__ out, int R, int C)
{
  __shared__ float tl[64][65];
  const long mat = blockIdx.z;
  in  += mat * (long)R * C;
  out += mat * (long)R * C;
  const int c0 = blockIdx.x * 64, r0 = blockIdx.y * 64;
  const int tid = threadIdx.x;
  const int lr = tid >> 4;          // 0..15
  const int lc4 = (tid & 15) * 4;   // 0,4,...,60
#pragma unroll
  for (int i = 0; i < 4; ++i) {
    const int r = lr + i * 16;
    const float4 v = *(const float4*)(in + (long)(r0 + r) * C + c0 + lc4);
    tl[r][lc4 + 0] = v.x; tl[r][lc4 + 1] = v.y; tl[r][lc4 + 2] = v.z; tl[r][lc4 + 3] = v.w;
  }
  __syncthreads();
#pragma unroll
  for (int i = 0; i < 4; ++i) {
    const int c = lr + i * 16;
    ushort4 o;
    o.x = __builtin_bit_cast(unsigned short, (__bf16)tl[lc4 + 0][c]);
    o.y = __builtin_bit_cast(unsigned short, (__bf16)tl[lc4 + 1][c]);
    o.z = __builtin_bit_cast(unsigned short, (__bf16)tl[lc4 + 2][c]);
    o.w = __builtin_bit_cast(unsigned short, (__bf16)tl[lc4 + 3][c]);
    *(ushort4*)((unsigned short*)out + (long)(c0 + c) * R + r0 + lc4) = o;
  }
}

// ---------------- combine: out[t] = sh_out[t] + pair_out[s0] + pair_out[s1] ----------------
__global__ __launch_bounds__(256) void combine_kernel(
    const bf16_t* __restrict__ sh_out, const bf16_t* __restrict__ pair_out,
    const int* __restrict__ inv_slot, float* __restrict__ out)
{
  const int t = blockIdx.x;
  const int c = threadIdx.x * 8;
  const int s0 = inv_slot[2 * t], s1 = inv_slot[2 * t + 1];
  const bf16x8 a = *(const bf16x8*)(sh_out  + (long)t  * HDIM + c);
  const bf16x8 b = *(const bf16x8*)(pair_out + (long)s0 * HDIM + c);
  const bf16x8 d = *(const bf16x8*)(pair_out + (long)s1 * HDIM + c);
  float4 o0, o1;
  o0.x = (float)a[0] + (float)b[0] + (float)d[0];
  o0.y = (float)a[1] + (float)b[1] + (float)d[1];
  o0.z = (float)a[2] + (float)b[2] + (float)d[2];
  o0.w = (float)a[3] + (float)b[3] + (float)d[3];
  o1.x = (float)a[4] + (float)b[4] + (float)d[4];
  o1.y = (float)a[5] + (float)b[5] + (float)d[5];
  o1.z = (float)a[6] + (float)b[6] + (float)d[6];
  o1.w = (float)a[7] + (float)b[7] + (float)d[7];
  *(float4*)(out + (long)t * HDIM + c) = o0;
  *(float4*)(out + (long)t * HDIM + c + 4) = o1;
}

// ---------------- fused-phase 128x128 MFMA GEMM, BK=64, register-prefetch pipeline --------
// PHASE 0 (up):   z==0: midsh = gelu(xb @ WshUt^T)           [M=4096,N=2048,K=2048]
//                 z>=1: midrt = gelu(xg_e @ WrtUt[e]^T)*w    [M=cnt_e,N=1024,K=2048]
// PHASE 1 (down): z==0: sh_out = midsh @ WshDt^T (k-seg)     [M=4096,N=2048,K=2048]
//                 z>=1: pair_out = midrt_e @ WrtDt[e]^T      [M=cnt_e,N=2048,K=1024]
// Merging both paths into one grid raises resident blocks/CU (latency hiding);
// the K-loop prefetches iter k+1's global loads into registers during iter k's MFMA.
template<int PHASE>
__global__ __launch_bounds__(256) void gemm_fused(
    const bf16_t* __restrict__ Ash, const bf16_t* __restrict__ Art,
    const bf16_t* __restrict__ Bsh, const bf16_t* __restrict__ Brt,
    bf16_t* __restrict__ Csh, bf16_t* __restrict__ Crt,
    const int* __restrict__ counts, const int* __restrict__ offsets,
    const float* __restrict__ pair_w)
{
  const int mt = blockIdx.x, nt = blockIdx.y;
  const bool is_sh = (blockIdx.z == 0);
  const int e = (int)blockIdx.z - 1;
  const int m0 = mt * 128;

  int K, lda, ldb, cnt = 0, segoff = 0;
  const bf16_t *Ab, *Bb;
  if (PHASE == 0) {
    if (is_sh) {
      K = 2048; lda = 2048; ldb = 2048;
      Ab = Ash + (long)m0 * 2048;
      Bb = Bsh + (long)nt * 128 * 2048;          // WshUt flat [2048][2048]
    } else {
      if (nt >= 8) return;                        // N=1024 for routed-up
      cnt = counts[e];
      if (m0 >= cnt) return;
      segoff = offsets[e];
      K = 2048; lda = 2048; ldb = 2048;
      Ab = Art + (long)(segoff + m0) * 2048;
      Bb = Brt + (long)e * (1024L * 2048) + (long)nt * 128 * 2048;
    }
  } else {
    if (is_sh) {
      K = 2048; lda = 2048; ldb = 1024;           // B k-segmented across the 2 shared experts
      Ab = Ash + (long)m0 * 2048;
      Bb = Bsh + (long)nt * 128 * 1024;
    } else {
      cnt = counts[e];
      if (m0 >= cnt) return;
      segoff = offsets[e];
      K = 1024; lda = 1024; ldb = 1024;
      Ab = Art + (long)(segoff + m0) * 1024;
      Bb = Brt + (long)e * (2048L * 1024) + (long)nt * 128 * 1024;
    }
  }

  __shared__ bf16_t As[128 * 72];
  __shared__ bf16_t Bs[128 * 72];

  const int tid = threadIdx.x;
  const int rr = tid >> 3, ch = tid & 7;
  const int lane = tid & 63, wv = tid >> 6;
  const int ln = lane & 15, quad = lane >> 4;
  const int wm = (wv & 1) * 64, wn = (wv >> 1) * 64;

  floatx4 acc[4][4];
#pragma unroll
  for (int i = 0; i < 4; ++i)
#pragma unroll
    for (int j = 0; j < 4; ++j) acc[i][j] = (floatx4){0.f, 0.f, 0.f, 0.f};

  bf16x8 av[4], bv[4];
  // prologue: issue k0=0 loads
  {
    long bk = (PHASE == 1 && is_sh) ? 0L : 0L;
#pragma unroll
    for (int i = 0; i < 4; ++i) {
      av[i] = *(const bf16x8*)(Ab + (long)(rr + i * 32) * lda + ch * 8);
      bv[i] = *(const bf16x8*)(Bb + (long)(rr + i * 32) * ldb + bk + ch * 8);
    }
  }

  for (int k0 = 0; k0 < K; k0 += 64) {
    __syncthreads();                 // prior iter's LDS reads complete
#pragma unroll
    for (int i = 0; i < 4; ++i) {    // commit prefetched regs to LDS (vmcnt wait here)
      *(bf16x8*)(&As[(rr + i * 32) * 72 + ch * 8]) = av[i];
      *(bf16x8*)(&Bs[(rr + i * 32) * 72 + ch * 8]) = bv[i];
    }
    __syncthreads();

    // prefetch next K-tile while this tile's MFMAs run
    const int kn = k0 + 64;
    if (kn < K) {
      long bk;
      if (PHASE == 1 && is_sh) bk = (long)(kn >> 10) * (2048L * 1024) + (kn & 1023);
      else bk = kn;
#pragma unroll
      for (int i = 0; i < 4; ++i) {
        av[i] = *(const bf16x8*)(Ab + (long)(rr + i * 32) * lda + kn + ch * 8);
        bv[i] = *(const bf16x8*)(Bb + (long)(rr + i * 32) * ldb + bk + ch * 8);
      }
    }

#pragma unroll
    for (int s = 0; s < 2; ++s) {
      bf16x8 af[4], bfr[4];
      const int ko = s * 32 + quad * 8;
#pragma unroll
      for (int mf = 0; mf < 4; ++mf) af[mf]  = *(const bf16x8*)(&As[(wm + mf * 16 + ln) * 72 + ko]);
#pragma unroll
      for (int nf = 0; nf < 4; ++nf) bfr[nf] = *(const bf16x8*)(&Bs[(wn + nf * 16 + ln) * 72 + ko]);
#pragma unroll
      for (int mf = 0; mf < 4; ++mf)
#pragma unroll
        for (int nf = 0; nf < 4; ++nf)
          acc[mf][nf] = __builtin_amdgcn_mfma_f32_16x16x32_bf16(af[mf], bfr[nf], acc[mf][nf], 0, 0, 0);
    }
  }

  // epilogue: D reg r -> row = quad*4+r, col = ln
#pragma unroll
  for (int mf = 0; mf < 4; ++mf) {
#pragma unroll
    for (int r = 0; r < 4; ++r) {
      const int rl = wm + mf * 16 + quad * 4 + r;
      const int gm = m0 + rl;
      if (!is_sh && gm >= cnt) continue;
      float wgt = 0.f;
      if (PHASE == 0 && !is_sh) wgt = pair_w[segoff + gm];
#pragma unroll
      for (int nf = 0; nf < 4; ++nf) {
        const int clg = nt * 128 + wn + nf * 16 + ln;
        const float v = acc[mf][nf][r];
        if (PHASE == 0) {
          if (is_sh) Csh[(long)gm * 2048 + clg] = (__bf16)gelu_f(v);
          else       Crt[(long)(segoff + gm) * 1024 + clg] = (__bf16)(gelu_f(v) * wgt);
        } else {
          if (is_sh) Csh[(long)gm * 2048 + clg] = (__bf16)v;
          else       Crt[(long)(segoff + gm) * 2048 + clg] = (__bf16)v;
        }
      }
    }
  }
}

extern "C" void kernel_launch(void* const* d_in, const int* in_sizes, int n_in,
                              void* d_out, int out_size, void* d_ws, size_t ws_size,
                              hipStream_t stream)
{
  (void)in_sizes; (void)n_in; (void)out_size; (void)ws_size;
  const float* x        = (const float*)d_in[0];
  const float* Wsh_up   = (const float*)d_in[1];
  const float* Wsh_down = (const float*)d_in[2];
  const float* Wrt_up   = (const float*)d_in[3];
  const float* Wrt_down = (const float*)d_in[4];
  const float* Wr       = (const float*)d_in[5];
  float* out = (float*)d_out;

  char* w = (char*)d_ws;
  size_t off = 0;
  auto alloc = [&](size_t bytes) -> void* {
    void* p = w + off;
    off = (off + bytes + 255) & ~(size_t)255;
    return p;
  };
  int*    counts  = (int*)alloc(64);
  int*    cursor  = (int*)alloc(64);
  int*    offsets = (int*)alloc(128);
  int*    top_e   = (int*)alloc((size_t)2 * T_TOK * 4);
  float*  top_w   = (float*)alloc((size_t)2 * T_TOK * 4);
  int*    pair_token = (int*)alloc((size_t)NPAIR_PAD * 4);
  float*  pair_w  = (float*)alloc((size_t)NPAIR_PAD * 4);
  int*    inv_slot = (int*)alloc((size_t)2 * T_TOK * 4);
  bf16_t* xb      = (bf16_t*)alloc((size_t)T_TOK * HDIM * 2);
  bf16_t* xg      = (bf16_t*)alloc((size_t)NPAIR_PAD * HDIM * 2);
  bf16_t* midsh   = (bf16_t*)alloc((size_t)T_TOK * (ESH * DDIM) * 2);
  bf16_t* midrt   = (bf16_t*)alloc((size_t)NPAIR_PAD * DDIM * 2);
  bf16_t* WshUt   = (bf16_t*)alloc((size_t)ESH * DDIM * HDIM * 2);  // [e][D][H] = flat [2048][2048]
  bf16_t* WshDt   = (bf16_t*)alloc((size_t)ESH * HDIM * DDIM * 2);  // [e][H][D]
  bf16_t* WrtUt   = (bf16_t*)alloc((size_t)ERT * DDIM * HDIM * 2);  // [e][D][H]
  bf16_t* WrtDt   = (bf16_t*)alloc((size_t)ERT * HDIM * DDIM * 2);  // [e][H][D]
  bf16_t* sh_out   = xb;   // xb dead after up-phase
  bf16_t* pair_out = xg;   // xg dead after up-phase

  hipMemsetAsync(w, 0, 768, stream);  // counts@0, cursor@256, offsets@512

  router_kernel<<<T_TOK, 256, 0, stream>>>(x, Wr, top_e, top_w, counts);
  prefix_kernel<<<1, 64, 0, stream>>>(counts, offsets);
  scatter_kernel<<<T_TOK / 256, 256, 0, stream>>>(top_e, top_w, offsets, cursor,
                                                  pair_token, pair_w, inv_slot);
  cast_x_kernel<<<T_TOK, 256, 0, stream>>>(x, xb);
  gather_kernel<<<NPAIR, 256, 0, stream>>>(x, pair_token, xg);

  transpose_cast_kernel<<<dim3(DDIM / 64, HDIM / 64, ESH), 256, 0, stream>>>(Wsh_up,   WshUt, HDIM, DDIM);
  transpose_cast_kernel<<<dim3(HDIM / 64, DDIM / 64, ESH), 256, 0, stream>>>(Wsh_down, WshDt, DDIM, HDIM);
  transpose_cast_kernel<<<dim3(DDIM / 64, HDIM / 64, ERT), 256, 0, stream>>>(Wrt_up,   WrtUt, HDIM, DDIM);
  transpose_cast_kernel<<<dim3(HDIM / 64, DDIM / 64, ERT), 256, 0, stream>>>(Wrt_down, WrtDt, DDIM, HDIM);

  // up phase: shared-up (z=0) + routed-up (z=1..16) in ONE dispatch
  gemm_fused<0><<<dim3(32, 16, 17), 256, 0, stream>>>(xb, xg, WshUt, WrtUt,
                                                      midsh, midrt, counts, offsets, pair_w);
  // down phase: shared-down (z=0) + routed-down (z=1..16) in ONE dispatch
  gemm_fused<1><<<dim3(32, 16, 17), 256, 0, stream>>>(midsh, midrt, WshDt, WrtDt,
                                                      sh_out, pair_out, counts, offsets, nullptr);

  combine_kernel<<<T_TOK, 256, 0, stream>>>(sh_out, pair_out, inv_slot, out);
}